// Round 1
// baseline (1225.386 us; speedup 1.0000x reference)
//
#include <hip/hip_runtime.h>

#define BB 8
#define SS 16
#define HH 32
#define DH 128
#define HD 4096
#define PAST 4080
#define TOT 4096
#define MM 128   // BB*SS

// d_out float offsets
#define OUT_O  0
#define ATTN_O 524288
#define K_O    17301504
#define V_O    151519232

// ws float offsets
#define QR_O 0
#define OH_O 524288
#define RT_O 1048576
#define PW_O 1050624

// ---------------- RoPE cos/sin table (f64 precision, 1024 angles) -------------
__global__ void rope_table_kernel(float* __restrict__ rt) {
  int t = threadIdx.x;            // 0..1023
  int s = t >> 6, j = t & 63;
  double inv = exp(-((double)(2 * j) / 128.0) * log(10000.0));
  double ang = (double)(PAST + s) * inv;
  rt[t] = (float)cos(ang);
  rt[1024 + t] = (float)sin(ang);
}

// ---------------- split-K SGEMM: P[mat][ks][m][n] partials --------------------
// grid = nmats*32*8 blocks of 256.  C[m][n] = sum_k A[m][k]*W[n][k]
__global__ __launch_bounds__(256) void gemm_splitk(
    const float* __restrict__ A, const float* __restrict__ W0,
    const float* __restrict__ W1, const float* __restrict__ W2,
    float* __restrict__ P) {
  int bx = blockIdx.x;
  int mat = bx >> 8;
  int rem = bx & 255;
  int nc = rem >> 3, ks = rem & 7;
  const float* Wm = (mat == 0) ? W0 : ((mat == 1) ? W1 : W2);
  int n0 = nc * 128;
  int tid = threadIdx.x;
  int tx = tid & 15, ty = tid >> 4;
  __shared__ __align__(16) float As[32][132];
  __shared__ __align__(16) float Bs[32][132];
  float acc[8][8];
#pragma unroll
  for (int i = 0; i < 8; ++i)
#pragma unroll
    for (int j = 0; j < 8; ++j) acc[i][j] = 0.f;

  int kg = tid & 7, rr = tid >> 3;   // staging: kg-fast -> coalesced global
  for (int kt = 0; kt < 16; ++kt) {
    int k0 = ks * 512 + kt * 32;
#pragma unroll
    for (int i = 0; i < 4; ++i) {
      int m = rr + i * 32;
      float4 va = *(const float4*)&A[(size_t)m * 4096 + k0 + kg * 4];
      As[kg * 4 + 0][m] = va.x; As[kg * 4 + 1][m] = va.y;
      As[kg * 4 + 2][m] = va.z; As[kg * 4 + 3][m] = va.w;
      float4 vb = *(const float4*)&Wm[(size_t)(n0 + m) * 4096 + k0 + kg * 4];
      Bs[kg * 4 + 0][m] = vb.x; Bs[kg * 4 + 1][m] = vb.y;
      Bs[kg * 4 + 2][m] = vb.z; Bs[kg * 4 + 3][m] = vb.w;
    }
    __syncthreads();
#pragma unroll 4
    for (int k = 0; k < 32; ++k) {
      const float4* ar = (const float4*)(&As[k][0]);
      const float4* br = (const float4*)(&Bs[k][0]);
      float4 a0 = ar[tx], a1 = ar[16 + tx];
      float4 b0 = br[ty], b1 = br[16 + ty];
      float av[8] = {a0.x, a0.y, a0.z, a0.w, a1.x, a1.y, a1.z, a1.w};
      float bv[8] = {b0.x, b0.y, b0.z, b0.w, b1.x, b1.y, b1.z, b1.w};
#pragma unroll
      for (int i = 0; i < 8; ++i)
#pragma unroll
        for (int j = 0; j < 8; ++j) acc[i][j] = fmaf(av[i], bv[j], acc[i][j]);
    }
    __syncthreads();
  }
  float* Pb = P + (size_t)(mat * 8 + ks) * 524288 + n0;
#pragma unroll
  for (int i = 0; i < 8; ++i) {
    int mi = (i < 4) ? (tx * 4 + i) : (64 + tx * 4 + (i - 4));
#pragma unroll
    for (int jh = 0; jh < 2; ++jh) {
      float4 o;
      o.x = acc[i][jh * 4 + 0]; o.y = acc[i][jh * 4 + 1];
      o.z = acc[i][jh * 4 + 2]; o.w = acc[i][jh * 4 + 3];
      *(float4*)&Pb[(size_t)mi * 4096 + jh * 64 + ty * 4] = o;
    }
  }
}

// ------------- QKV partial-reduce + bias + RoPE + scatter ---------------------
__global__ __launch_bounds__(256) void qkv_reduce(
    const float* __restrict__ P, const float* __restrict__ bq,
    const float* __restrict__ bk, const float* __restrict__ bv,
    const float* __restrict__ rt, float* __restrict__ qr,
    float* __restrict__ kout, float* __restrict__ vout) {
  int t = blockIdx.x * 256 + threadIdx.x;   // < 3*2^18
  int d2 = t & 63;
  int h = (t >> 6) & 31;
  int m = (t >> 11) & 127;
  int mat = t >> 18;
  int n1 = h * 128 + d2, n2 = n1 + 64;
  const float* bias = (mat == 0) ? bq : ((mat == 1) ? bk : bv);
  float v1 = bias[n1], v2 = bias[n2];
  const float* Pm = P + (size_t)(mat * 8) * 524288 + (size_t)m * 4096;
#pragma unroll
  for (int s = 0; s < 8; ++s) {
    v1 += Pm[(size_t)s * 524288 + n1];
    v2 += Pm[(size_t)s * 524288 + n2];
  }
  int st = m & 15, b = m >> 4;
  int bh = b * 32 + h;
  if (mat == 2) {
    size_t dst = (size_t)(bh * TOT + PAST + st) * 128;
    vout[dst + d2] = v1; vout[dst + 64 + d2] = v2;
  } else {
    float c = rt[st * 64 + d2], sn = rt[1024 + st * 64 + d2];
    float o1 = v1 * c - v2 * sn;
    float o2 = v2 * c + v1 * sn;
    if (mat == 0) {
      size_t dst = (size_t)(bh * 16 + st) * 128;
      qr[dst + d2] = o1; qr[dst + 64 + d2] = o2;
    } else {
      size_t dst = (size_t)(bh * TOT + PAST + st) * 128;
      kout[dst + d2] = o1; kout[dst + 64 + d2] = o2;
    }
  }
}

// ------------- fused past_key copy + QK^T logits ------------------------------
// grid = 256 bh * 32 kchunks; 128 keys per block staged transposed in LDS
__global__ __launch_bounds__(256) void scores_kernel(
    const float* __restrict__ pastk, const float* __restrict__ qr,
    float* __restrict__ kout, float* __restrict__ attn) {
  int bh = blockIdx.x >> 5, kc = blockIdx.x & 31;
  int r0 = kc * 128;
  int tid = threadIdx.x;
  __shared__ float KsT[64][129];   // [d-local][key] transposed
  __shared__ float Qs[2048];
#pragma unroll
  for (int i = 0; i < 8; ++i)
    Qs[tid + i * 256] = qr[(size_t)bh * 2048 + tid + i * 256];

  const float4* pk4 = (const float4*)pastk;
  float4* ko4 = (float4*)kout;
  int qg = tid >> 6, lane = tid & 63;
  float acc[4][2] = {{0.f, 0.f}, {0.f, 0.f}, {0.f, 0.f}, {0.f, 0.f}};

  for (int p = 0; p < 2; ++p) {    // two halves of d (0..63, 64..127)
    if (p) __syncthreads();
#pragma unroll
    for (int i = 0; i < 8; ++i) {
      int f = tid + i * 256;       // 0..2047
      int r = f >> 4, g16 = f & 15;
      int g = g16 + p * 16;
      int row = r0 + r;
      float4 v;
      size_t kidx = (size_t)(bh * TOT + row) * 32 + g;
      if (row < PAST) {
        v = pk4[(size_t)(bh * PAST + row) * 32 + g];
        ko4[kidx] = v;
      } else {
        v = ko4[kidx];             // new rows written by qkv_reduce
      }
      int dl = g16 * 4;
      KsT[dl][r] = v.x; KsT[dl + 1][r] = v.y;
      KsT[dl + 2][r] = v.z; KsT[dl + 3][r] = v.w;
    }
    __syncthreads();
    int dbase = p * 64;
#pragma unroll 4
    for (int d = 0; d < 64; ++d) {
      float k0v = KsT[d][lane], k1v = KsT[d][lane + 64];
#pragma unroll
      for (int j = 0; j < 4; ++j) {
        float qv = Qs[(qg * 4 + j) * 128 + dbase + d];
        acc[j][0] = fmaf(qv, k0v, acc[j][0]);
        acc[j][1] = fmaf(qv, k1v, acc[j][1]);
      }
    }
  }
  const float scale = 0.088388347648318447f;  // 1/sqrt(128)
#pragma unroll
  for (int j = 0; j < 4; ++j) {
    int q = qg * 4 + j;
    size_t base = (size_t)(bh * 16 + q) * 4096 + r0;
    attn[base + lane] = acc[j][0] * scale;
    attn[base + 64 + lane] = acc[j][1] * scale;
  }
}

// ------------- in-place row softmax (rows of 4096) ----------------------------
__global__ __launch_bounds__(256) void softmax_kernel(float* __restrict__ attn) {
  int row = blockIdx.x;
  float4* a4 = (float4*)(attn + (size_t)row * 4096);
  int tid = threadIdx.x;
  float4 v[4];
  float mx = -1e30f;
#pragma unroll
  for (int i = 0; i < 4; ++i) {
    v[i] = a4[tid + i * 256];
    mx = fmaxf(mx, fmaxf(fmaxf(v[i].x, v[i].y), fmaxf(v[i].z, v[i].w)));
  }
#pragma unroll
  for (int off = 32; off; off >>= 1) mx = fmaxf(mx, __shfl_xor(mx, off));
  __shared__ float redm[4];
  __shared__ float reds[4];
  int wid = tid >> 6;
  if ((tid & 63) == 0) redm[wid] = mx;
  __syncthreads();
  mx = fmaxf(fmaxf(redm[0], redm[1]), fmaxf(redm[2], redm[3]));
  float sum = 0.f;
#pragma unroll
  for (int i = 0; i < 4; ++i) {
    v[i].x = __expf(v[i].x - mx); v[i].y = __expf(v[i].y - mx);
    v[i].z = __expf(v[i].z - mx); v[i].w = __expf(v[i].w - mx);
    sum += v[i].x + v[i].y + v[i].z + v[i].w;
  }
#pragma unroll
  for (int off = 32; off; off >>= 1) sum += __shfl_xor(sum, off);
  if ((tid & 63) == 0) reds[wid] = sum;
  __syncthreads();
  sum = reds[0] + reds[1] + reds[2] + reds[3];
  float inv = 1.f / sum;
#pragma unroll
  for (int i = 0; i < 4; ++i) {
    v[i].x *= inv; v[i].y *= inv; v[i].z *= inv; v[i].w *= inv;
    a4[tid + i * 256] = v[i];
  }
}

// ------------- fused past_value copy + attn@V ---------------------------------
// one block (512 thr) per bh; deterministic LDS reduction over 4 k-groups
__global__ __launch_bounds__(512) void pv_kernel(
    const float* __restrict__ pastv, const float* __restrict__ attn,
    float* __restrict__ vout, float* __restrict__ oh) {
  int bh = blockIdx.x;
  int b = bh >> 5, h = bh & 31;
  int tid = threadIdx.x;
  int d = tid & 127, kg = tid >> 7;   // kg 0..3
  __shared__ float atn[16][256];
  __shared__ float red[4][16][128];
  float acc[16];
#pragma unroll
  for (int q = 0; q < 16; ++q) acc[q] = 0.f;

  for (int kc = 0; kc < 16; ++kc) {   // chunks of 256 keys
#pragma unroll
    for (int i = 0; i < 8; ++i) {
      int idx = tid + i * 512;        // 0..4095
      int q = idx >> 8, kk = idx & 255;
      atn[q][kk] = attn[(size_t)(bh * 16 + q) * 4096 + kc * 256 + kk];
    }
    __syncthreads();
    int rbase = kc * 256 + kg * 64;
#pragma unroll 4
    for (int t = 0; t < 64; ++t) {
      int row = rbase + t;
      float v;
      size_t oidx = (size_t)(bh * TOT + row) * 128 + d;
      if (row < PAST) {
        v = pastv[(size_t)(bh * PAST + row) * 128 + d];
        vout[oidx] = v;
      } else {
        v = vout[oidx];               // new rows written by qkv_reduce
      }
      int kk = kg * 64 + t;
#pragma unroll
      for (int q = 0; q < 16; ++q) acc[q] = fmaf(atn[q][kk], v, acc[q]);
    }
    __syncthreads();
  }
#pragma unroll
  for (int q = 0; q < 16; ++q) red[kg][q][d] = acc[q];
  __syncthreads();
#pragma unroll
  for (int rep = 0; rep < 4; ++rep) {
    int o = tid + rep * 512;          // 0..2047
    int q = o >> 7, dd = o & 127;
    float s = red[0][q][dd] + red[1][q][dd] + red[2][q][dd] + red[3][q][dd];
    oh[(size_t)(b * 16 + q) * 4096 + h * 128 + dd] = s;
  }
}

// ------------- Wo partial-reduce + bias ---------------------------------------
__global__ __launch_bounds__(256) void out_reduce(
    const float* __restrict__ P, const float* __restrict__ bo,
    float* __restrict__ out) {
  int t = blockIdx.x * 256 + threadIdx.x;  // < 524288
  float v = bo[t & 4095];
#pragma unroll
  for (int s = 0; s < 8; ++s) v += P[(size_t)s * 524288 + t];
  out[t] = v;
}

extern "C" void kernel_launch(void* const* d_in, const int* in_sizes, int n_in,
                              void* d_out, int out_size, void* d_ws, size_t ws_size,
                              hipStream_t stream) {
  const float* x     = (const float*)d_in[0];
  const float* pastk = (const float*)d_in[1];
  const float* pastv = (const float*)d_in[2];
  const float* Wq = (const float*)d_in[3];
  const float* bq = (const float*)d_in[4];
  const float* Wk = (const float*)d_in[5];
  const float* bk = (const float*)d_in[6];
  const float* Wv = (const float*)d_in[7];
  const float* bv = (const float*)d_in[8];
  const float* Wo = (const float*)d_in[9];
  const float* bo = (const float*)d_in[10];

  float* out  = (float*)d_out;
  float* attn = out + ATTN_O;
  float* kout = out + K_O;
  float* vout = out + V_O;

  float* ws = (float*)d_ws;
  float* qr = ws + QR_O;
  float* oh = ws + OH_O;
  float* rt = ws + RT_O;
  float* pw = ws + PW_O;

  rope_table_kernel<<<1, 1024, 0, stream>>>(rt);
  // QKV projections: partials stored in (not-yet-final) attn region of d_out
  gemm_splitk<<<768, 256, 0, stream>>>(x, Wq, Wk, Wv, attn);
  qkv_reduce<<<3072, 256, 0, stream>>>(attn, bq, bk, bv, rt, qr, kout, vout);
  scores_kernel<<<8192, 256, 0, stream>>>(pastk, qr, kout, attn);
  softmax_kernel<<<4096, 256, 0, stream>>>(attn);
  pv_kernel<<<256, 512, 0, stream>>>(pastv, attn, vout, oh);
  gemm_splitk<<<256, 256, 0, stream>>>(oh, Wo, Wo, Wo, pw);
  out_reduce<<<2048, 256, 0, stream>>>(pw, bo, out);
}

// Round 2
// 844.489 us; speedup vs baseline: 1.4510x; 1.4510x over previous
//
#include <hip/hip_runtime.h>

#define BB 8
#define SS 16
#define HH 32
#define DH 128
#define HD 4096
#define PAST 4080
#define TOT 4096
#define MM 128   // BB*SS

// d_out float offsets
#define OUT_O  0
#define ATTN_O 524288
#define K_O    17301504
#define V_O    151519232

// ws float offsets
#define QR_O 0
#define OH_O 524288
#define RT_O 1048576
#define PW_O 1050624   // Wo-GEMM partials; ALSO reused earlier as pv partials

// ---------------- RoPE cos/sin table (f64 precision, 1024 angles) -------------
__global__ void rope_table_kernel(float* __restrict__ rt) {
  int t = threadIdx.x;            // 0..1023
  int s = t >> 6, j = t & 63;
  double inv = exp(-((double)(2 * j) / 128.0) * log(10000.0));
  double ang = (double)(PAST + s) * inv;
  rt[t] = (float)cos(ang);
  rt[1024 + t] = (float)sin(ang);
}

// ---------------- split-K SGEMM: P[mat][ks][m][n] partials --------------------
// grid = nmats*32*8 blocks of 256.  C[m][n] = sum_k A[m][k]*W[n][k]
__global__ __launch_bounds__(256) void gemm_splitk(
    const float* __restrict__ A, const float* __restrict__ W0,
    const float* __restrict__ W1, const float* __restrict__ W2,
    float* __restrict__ P) {
  int bx = blockIdx.x;
  int mat = bx >> 8;
  int rem = bx & 255;
  int nc = rem >> 3, ks = rem & 7;
  const float* Wm = (mat == 0) ? W0 : ((mat == 1) ? W1 : W2);
  int n0 = nc * 128;
  int tid = threadIdx.x;
  int tx = tid & 15, ty = tid >> 4;
  __shared__ __align__(16) float As[32][132];
  __shared__ __align__(16) float Bs[32][132];
  float acc[8][8];
#pragma unroll
  for (int i = 0; i < 8; ++i)
#pragma unroll
    for (int j = 0; j < 8; ++j) acc[i][j] = 0.f;

  int kg = tid & 7, rr = tid >> 3;   // staging: kg-fast -> coalesced global
  for (int kt = 0; kt < 16; ++kt) {
    int k0 = ks * 512 + kt * 32;
#pragma unroll
    for (int i = 0; i < 4; ++i) {
      int m = rr + i * 32;
      float4 va = *(const float4*)&A[(size_t)m * 4096 + k0 + kg * 4];
      As[kg * 4 + 0][m] = va.x; As[kg * 4 + 1][m] = va.y;
      As[kg * 4 + 2][m] = va.z; As[kg * 4 + 3][m] = va.w;
      float4 vb = *(const float4*)&Wm[(size_t)(n0 + m) * 4096 + k0 + kg * 4];
      Bs[kg * 4 + 0][m] = vb.x; Bs[kg * 4 + 1][m] = vb.y;
      Bs[kg * 4 + 2][m] = vb.z; Bs[kg * 4 + 3][m] = vb.w;
    }
    __syncthreads();
#pragma unroll 4
    for (int k = 0; k < 32; ++k) {
      const float4* ar = (const float4*)(&As[k][0]);
      const float4* br = (const float4*)(&Bs[k][0]);
      float4 a0 = ar[tx], a1 = ar[16 + tx];
      float4 b0 = br[ty], b1 = br[16 + ty];
      float av[8] = {a0.x, a0.y, a0.z, a0.w, a1.x, a1.y, a1.z, a1.w};
      float bv[8] = {b0.x, b0.y, b0.z, b0.w, b1.x, b1.y, b1.z, b1.w};
#pragma unroll
      for (int i = 0; i < 8; ++i)
#pragma unroll
        for (int j = 0; j < 8; ++j) acc[i][j] = fmaf(av[i], bv[j], acc[i][j]);
    }
    __syncthreads();
  }
  float* Pb = P + (size_t)(mat * 8 + ks) * 524288 + n0;
#pragma unroll
  for (int i = 0; i < 8; ++i) {
    int mi = (i < 4) ? (tx * 4 + i) : (64 + tx * 4 + (i - 4));
#pragma unroll
    for (int jh = 0; jh < 2; ++jh) {
      float4 o;
      o.x = acc[i][jh * 4 + 0]; o.y = acc[i][jh * 4 + 1];
      o.z = acc[i][jh * 4 + 2]; o.w = acc[i][jh * 4 + 3];
      *(float4*)&Pb[(size_t)mi * 4096 + jh * 64 + ty * 4] = o;
    }
  }
}

// ------------- QKV partial-reduce + bias + RoPE + scatter ---------------------
__global__ __launch_bounds__(256) void qkv_reduce(
    const float* __restrict__ P, const float* __restrict__ bq,
    const float* __restrict__ bk, const float* __restrict__ bv,
    const float* __restrict__ rt, float* __restrict__ qr,
    float* __restrict__ kout, float* __restrict__ vout) {
  int t = blockIdx.x * 256 + threadIdx.x;   // < 3*2^18
  int d2 = t & 63;
  int h = (t >> 6) & 31;
  int m = (t >> 11) & 127;
  int mat = t >> 18;
  int n1 = h * 128 + d2, n2 = n1 + 64;
  const float* bias = (mat == 0) ? bq : ((mat == 1) ? bk : bv);
  float v1 = bias[n1], v2 = bias[n2];
  const float* Pm = P + (size_t)(mat * 8) * 524288 + (size_t)m * 4096;
#pragma unroll
  for (int s = 0; s < 8; ++s) {
    v1 += Pm[(size_t)s * 524288 + n1];
    v2 += Pm[(size_t)s * 524288 + n2];
  }
  int st = m & 15, b = m >> 4;
  int bh = b * 32 + h;
  if (mat == 2) {
    size_t dst = (size_t)(bh * TOT + PAST + st) * 128;
    vout[dst + d2] = v1; vout[dst + 64 + d2] = v2;
  } else {
    float c = rt[st * 64 + d2], sn = rt[1024 + st * 64 + d2];
    float o1 = v1 * c - v2 * sn;
    float o2 = v2 * c + v1 * sn;
    if (mat == 0) {
      size_t dst = (size_t)(bh * 16 + st) * 128;
      qr[dst + d2] = o1; qr[dst + 64 + d2] = o2;
    } else {
      size_t dst = (size_t)(bh * TOT + PAST + st) * 128;
      kout[dst + d2] = o1; kout[dst + 64 + d2] = o2;
    }
  }
}

// ------------- fused past_key copy + QK^T logits ------------------------------
// grid = 256 bh * 32 kchunks; 128 keys per block staged transposed in LDS
__global__ __launch_bounds__(256) void scores_kernel(
    const float* __restrict__ pastk, const float* __restrict__ qr,
    float* __restrict__ kout, float* __restrict__ attn) {
  int bh = blockIdx.x >> 5, kc = blockIdx.x & 31;
  int r0 = kc * 128;
  int tid = threadIdx.x;
  __shared__ float KsT[64][129];   // [d-local][key] transposed
  __shared__ float Qs[2048];
#pragma unroll
  for (int i = 0; i < 8; ++i)
    Qs[tid + i * 256] = qr[(size_t)bh * 2048 + tid + i * 256];

  const float4* pk4 = (const float4*)pastk;
  float4* ko4 = (float4*)kout;
  int qg = tid >> 6, lane = tid & 63;
  float acc[4][2] = {{0.f, 0.f}, {0.f, 0.f}, {0.f, 0.f}, {0.f, 0.f}};

  for (int p = 0; p < 2; ++p) {    // two halves of d (0..63, 64..127)
    if (p) __syncthreads();
#pragma unroll
    for (int i = 0; i < 8; ++i) {
      int f = tid + i * 256;       // 0..2047
      int r = f >> 4, g16 = f & 15;
      int g = g16 + p * 16;
      int row = r0 + r;
      float4 v;
      size_t kidx = (size_t)(bh * TOT + row) * 32 + g;
      if (row < PAST) {
        v = pk4[(size_t)(bh * PAST + row) * 32 + g];
        ko4[kidx] = v;
      } else {
        v = ko4[kidx];             // new rows written by qkv_reduce
      }
      int dl = g16 * 4;
      KsT[dl][r] = v.x; KsT[dl + 1][r] = v.y;
      KsT[dl + 2][r] = v.z; KsT[dl + 3][r] = v.w;
    }
    __syncthreads();
    int dbase = p * 64;
#pragma unroll 4
    for (int d = 0; d < 64; ++d) {
      float k0v = KsT[d][lane], k1v = KsT[d][lane + 64];
#pragma unroll
      for (int j = 0; j < 4; ++j) {
        float qv = Qs[(qg * 4 + j) * 128 + dbase + d];
        acc[j][0] = fmaf(qv, k0v, acc[j][0]);
        acc[j][1] = fmaf(qv, k1v, acc[j][1]);
      }
    }
  }
  const float scale = 0.088388347648318447f;  // 1/sqrt(128)
#pragma unroll
  for (int j = 0; j < 4; ++j) {
    int q = qg * 4 + j;
    size_t base = (size_t)(bh * 16 + q) * 4096 + r0;
    attn[base + lane] = acc[j][0] * scale;
    attn[base + 64 + lane] = acc[j][1] * scale;
  }
}

// ------------- in-place row softmax (rows of 4096) ----------------------------
__global__ __launch_bounds__(256) void softmax_kernel(float* __restrict__ attn) {
  int row = blockIdx.x;
  float4* a4 = (float4*)(attn + (size_t)row * 4096);
  int tid = threadIdx.x;
  float4 v[4];
  float mx = -1e30f;
#pragma unroll
  for (int i = 0; i < 4; ++i) {
    v[i] = a4[tid + i * 256];
    mx = fmaxf(mx, fmaxf(fmaxf(v[i].x, v[i].y), fmaxf(v[i].z, v[i].w)));
  }
#pragma unroll
  for (int off = 32; off; off >>= 1) mx = fmaxf(mx, __shfl_xor(mx, off));
  __shared__ float redm[4];
  __shared__ float reds[4];
  int wid = tid >> 6;
  if ((tid & 63) == 0) redm[wid] = mx;
  __syncthreads();
  mx = fmaxf(fmaxf(redm[0], redm[1]), fmaxf(redm[2], redm[3]));
  float sum = 0.f;
#pragma unroll
  for (int i = 0; i < 4; ++i) {
    v[i].x = __expf(v[i].x - mx); v[i].y = __expf(v[i].y - mx);
    v[i].z = __expf(v[i].z - mx); v[i].w = __expf(v[i].w - mx);
    sum += v[i].x + v[i].y + v[i].z + v[i].w;
  }
#pragma unroll
  for (int off = 32; off; off >>= 1) sum += __shfl_xor(sum, off);
  if ((tid & 63) == 0) reds[wid] = sum;
  __syncthreads();
  sum = reds[0] + reds[1] + reds[2] + reds[3];
  float inv = 1.f / sum;
#pragma unroll
  for (int i = 0; i < 4; ++i) {
    v[i].x *= inv; v[i].y *= inv; v[i].z *= inv; v[i].w *= inv;
    a4[tid + i * 256] = v[i];
  }
}

// ------------- fused past_value copy + attn@V, split over 4 key-chunks --------
// grid = 256 bh * 4 chunks of 1024 keys; 256 threads; float4 over d
__global__ __launch_bounds__(256) void pv_kernel(
    const float* __restrict__ pastv, const float* __restrict__ attn,
    float* __restrict__ vout, float* __restrict__ pvp) {
  int blk = blockIdx.x;
  int bh = blk >> 2, nc = blk & 3;
  int tid = threadIdx.x;
  int dq = tid & 31, rg = tid >> 5;      // dq: float4-in-d, rg: row group 0..7
  __shared__ float atn[16][256];          // 16 KB
  __shared__ float red[4][16][128];       // 32 KB
  float acc[16][4];
#pragma unroll
  for (int q = 0; q < 16; ++q)
#pragma unroll
    for (int j = 0; j < 4; ++j) acc[q][j] = 0.f;

  const float4* pv4 = (const float4*)pastv;
  float4* vo4 = (float4*)vout;
  int base0 = nc * 1024;

  for (int slab = 0; slab < 4; ++slab) {  // 256 keys per slab
    int kbase = base0 + slab * 256;
#pragma unroll
    for (int q = 0; q < 16; ++q)
      atn[q][tid] = attn[(size_t)(bh * 16 + q) * 4096 + kbase + tid];
    __syncthreads();
#pragma unroll 4
    for (int it = 0; it < 32; ++it) {     // 8 rows per iteration
      int kk = it * 8 + rg;               // local key in slab
      int row = kbase + kk;
      float4 v;
      size_t oidx = (size_t)(bh * TOT + row) * 32 + dq;
      if (row < PAST) {
        v = pv4[(size_t)(bh * PAST + row) * 32 + dq];
        vo4[oidx] = v;
      } else {
        v = vo4[oidx];                    // new rows written by qkv_reduce
      }
#pragma unroll
      for (int q = 0; q < 16; ++q) {
        float a = atn[q][kk];
        acc[q][0] = fmaf(a, v.x, acc[q][0]);
        acc[q][1] = fmaf(a, v.y, acc[q][1]);
        acc[q][2] = fmaf(a, v.z, acc[q][2]);
        acc[q][3] = fmaf(a, v.w, acc[q][3]);
      }
    }
    __syncthreads();
  }
  // combine the two row-groups within each wave (lanes l and l^32)
#pragma unroll
  for (int q = 0; q < 16; ++q)
#pragma unroll
    for (int j = 0; j < 4; ++j) acc[q][j] += __shfl_xor(acc[q][j], 32);
  int wid = tid >> 6;
  if ((tid & 63) < 32) {
#pragma unroll
    for (int q = 0; q < 16; ++q) {
      float4 o; o.x = acc[q][0]; o.y = acc[q][1]; o.z = acc[q][2]; o.w = acc[q][3];
      *(float4*)&red[wid][q][dq * 4] = o;
    }
  }
  __syncthreads();
#pragma unroll
  for (int rep = 0; rep < 8; ++rep) {
    int o = tid + rep * 256;              // 0..2047
    int q = o >> 7, dd = o & 127;
    float s = red[0][q][dd] + red[1][q][dd] + red[2][q][dd] + red[3][q][dd];
    pvp[((size_t)(bh * 4 + nc) * 16 + q) * 128 + dd] = s;
  }
}

// ------------- pv partial reduce -> oh ---------------------------------------
__global__ __launch_bounds__(256) void pv_reduce(
    const float* __restrict__ pvp, float* __restrict__ oh) {
  int t = blockIdx.x * 256 + threadIdx.x;  // < 524288
  int dd = t & 127;
  int q = (t >> 7) & 15;
  int bh = t >> 11;
  int b = bh >> 5, h = bh & 31;
  float s = 0.f;
#pragma unroll
  for (int nc = 0; nc < 4; ++nc)
    s += pvp[((size_t)(bh * 4 + nc) * 16 + q) * 128 + dd];
  oh[(size_t)(b * 16 + q) * 4096 + h * 128 + dd] = s;
}

// ------------- Wo partial-reduce + bias ---------------------------------------
__global__ __launch_bounds__(256) void out_reduce(
    const float* __restrict__ P, const float* __restrict__ bo,
    float* __restrict__ out) {
  int t = blockIdx.x * 256 + threadIdx.x;  // < 524288
  float v = bo[t & 4095];
#pragma unroll
  for (int s = 0; s < 8; ++s) v += P[(size_t)s * 524288 + t];
  out[t] = v;
}

extern "C" void kernel_launch(void* const* d_in, const int* in_sizes, int n_in,
                              void* d_out, int out_size, void* d_ws, size_t ws_size,
                              hipStream_t stream) {
  const float* x     = (const float*)d_in[0];
  const float* pastk = (const float*)d_in[1];
  const float* pastv = (const float*)d_in[2];
  const float* Wq = (const float*)d_in[3];
  const float* bq = (const float*)d_in[4];
  const float* Wk = (const float*)d_in[5];
  const float* bk = (const float*)d_in[6];
  const float* Wv = (const float*)d_in[7];
  const float* bv = (const float*)d_in[8];
  const float* Wo = (const float*)d_in[9];
  const float* bo = (const float*)d_in[10];

  float* out  = (float*)d_out;
  float* attn = out + ATTN_O;
  float* kout = out + K_O;
  float* vout = out + V_O;

  float* ws = (float*)d_ws;
  float* qr = ws + QR_O;
  float* oh = ws + OH_O;
  float* rt = ws + RT_O;
  float* pw = ws + PW_O;   // Wo partials; earlier in the stream: pv partials

  rope_table_kernel<<<1, 1024, 0, stream>>>(rt);
  // QKV projections: partials stored in (not-yet-final) attn region of d_out
  gemm_splitk<<<768, 256, 0, stream>>>(x, Wq, Wk, Wv, attn);
  qkv_reduce<<<3072, 256, 0, stream>>>(attn, bq, bk, bv, rt, qr, kout, vout);
  scores_kernel<<<8192, 256, 0, stream>>>(pastk, qr, kout, attn);
  softmax_kernel<<<4096, 256, 0, stream>>>(attn);
  pv_kernel<<<1024, 256, 0, stream>>>(pastv, attn, vout, pw);
  pv_reduce<<<2048, 256, 0, stream>>>(pw, oh);
  gemm_splitk<<<256, 256, 0, stream>>>(oh, Wo, Wo, Wo, pw);
  out_reduce<<<2048, 256, 0, stream>>>(pw, bo, out);
}

// Round 3
// 739.181 us; speedup vs baseline: 1.6578x; 1.1425x over previous
//
#include <hip/hip_runtime.h>
#include <hip/hip_bf16.h>

#define BB 8
#define SS 16
#define HH 32
#define DH 128
#define HD 4096
#define PAST 4080
#define TOT 4096
#define MM 128   // BB*SS

// d_out float offsets
#define OUT_O  0
#define ATTN_O 524288
#define K_O    17301504
#define V_O    151519232

// ws float offsets
#define QR_O 0
#define OH_O 524288
#define RT_O 1048576
#define PW_O 1050624   // Wo-GEMM partials; ALSO reused earlier as pv partials

typedef __attribute__((ext_vector_type(8))) short short8;
typedef __attribute__((ext_vector_type(4))) float f32x4;

static __device__ inline unsigned short f2bf(float x) {
  __hip_bfloat16 h = __float2bfloat16(x);
  return *reinterpret_cast<unsigned short*>(&h);
}

// ---------------- RoPE cos/sin table (f64 precision, 1024 angles) -------------
__global__ void rope_table_kernel(float* __restrict__ rt) {
  int t = threadIdx.x;            // 0..1023
  int s = t >> 6, j = t & 63;
  double inv = exp(-((double)(2 * j) / 128.0) * log(10000.0));
  double ang = (double)(PAST + s) * inv;
  rt[t] = (float)cos(ang);
  rt[1024 + t] = (float)sin(ang);
}

// ------------- split-K MFMA bf16 GEMM: P[mat][ks][m][n] partials --------------
// grid = nmats*256 blocks of 256.  C[m][n] = sum_k A[m][k]*W[n][k]
// 128x128 tile, K-slice 512 per ks, BK=64, 4 waves in 2x2, in-reg f32->bf16.
#define LDP 72   // padded LDS row stride in bf16 elements (144 B)
__global__ __launch_bounds__(256) void gemm_mfma(
    const float* __restrict__ A, const float* __restrict__ W0,
    const float* __restrict__ W1, const float* __restrict__ W2,
    float* __restrict__ P) {
  int bx = blockIdx.x;
  int mat = bx >> 8;
  int rem = bx & 255;
  int nc = rem >> 3, ks = rem & 7;
  const float* Wm = (mat == 0) ? W0 : ((mat == 1) ? W1 : W2);
  int n0 = nc * 128;
  int tid = threadIdx.x;
  int lane = tid & 63, wid = tid >> 6;
  int wm = wid >> 1, wn = wid & 1;       // 2x2 wave grid, each 64x64
  int l15 = lane & 15, l4 = lane >> 4;

  __shared__ unsigned short As[128 * LDP];
  __shared__ unsigned short Bs[128 * LDP];

  f32x4 acc[4][4];
#pragma unroll
  for (int i = 0; i < 4; ++i)
#pragma unroll
    for (int j = 0; j < 4; ++j) acc[i][j] = (f32x4){0.f, 0.f, 0.f, 0.f};

  int srow = tid >> 1;                    // 0..127
  int skh = (tid & 1) * 32;               // k half within BK=64

  for (int kt = 0; kt < 8; ++kt) {
    int k0 = ks * 512 + kt * 64;
    const float* Ap = &A[(size_t)srow * 4096 + k0 + skh];
    const float* Wp = &Wm[(size_t)(n0 + srow) * 4096 + k0 + skh];
    // issue global loads before the barrier so they overlap prior compute
    float4 va[8], vb[8];
#pragma unroll
    for (int i = 0; i < 8; ++i) {
      va[i] = *(const float4*)(Ap + 4 * i);
      vb[i] = *(const float4*)(Wp + 4 * i);
    }
    __syncthreads();                      // prev-iter LDS reads done
    unsigned short* Asp = &As[srow * LDP + skh];
    unsigned short* Bsp = &Bs[srow * LDP + skh];
#pragma unroll
    for (int i = 0; i < 8; ++i) {
      ushort4 ua, ub;
      ua.x = f2bf(va[i].x); ua.y = f2bf(va[i].y);
      ua.z = f2bf(va[i].z); ua.w = f2bf(va[i].w);
      ub.x = f2bf(vb[i].x); ub.y = f2bf(vb[i].y);
      ub.z = f2bf(vb[i].z); ub.w = f2bf(vb[i].w);
      *(ushort4*)(Asp + 4 * i) = ua;
      *(ushort4*)(Bsp + 4 * i) = ub;
    }
    __syncthreads();
#pragma unroll
    for (int s = 0; s < 2; ++s) {         // two K=32 steps within BK=64
      short8 af[4], bf[4];
#pragma unroll
      for (int f = 0; f < 4; ++f) {
        int ar = wm * 64 + f * 16 + l15;
        af[f] = *(const short8*)&As[ar * LDP + s * 32 + l4 * 8];
        int br = wn * 64 + f * 16 + l15;
        bf[f] = *(const short8*)&Bs[br * LDP + s * 32 + l4 * 8];
      }
#pragma unroll
      for (int i = 0; i < 4; ++i)
#pragma unroll
        for (int j = 0; j < 4; ++j)
          acc[i][j] = __builtin_amdgcn_mfma_f32_16x16x32_bf16(
              af[i], bf[j], acc[i][j], 0, 0, 0);
    }
  }

  float* Pb = P + (size_t)(mat * 8 + ks) * 524288 + n0;
#pragma unroll
  for (int i = 0; i < 4; ++i) {
#pragma unroll
    for (int j = 0; j < 4; ++j) {
      int mbase = wm * 64 + i * 16 + l4 * 4;
      int nn = wn * 64 + j * 16 + l15;
#pragma unroll
      for (int r = 0; r < 4; ++r)
        Pb[(size_t)(mbase + r) * 4096 + nn] = acc[i][j][r];
    }
  }
}

// ------------- QKV partial-reduce + bias + RoPE + scatter ---------------------
__global__ __launch_bounds__(256) void qkv_reduce(
    const float* __restrict__ P, const float* __restrict__ bq,
    const float* __restrict__ bk, const float* __restrict__ bv,
    const float* __restrict__ rt, float* __restrict__ qr,
    float* __restrict__ kout, float* __restrict__ vout) {
  int t = blockIdx.x * 256 + threadIdx.x;   // < 3*2^18
  int d2 = t & 63;
  int h = (t >> 6) & 31;
  int m = (t >> 11) & 127;
  int mat = t >> 18;
  int n1 = h * 128 + d2, n2 = n1 + 64;
  const float* bias = (mat == 0) ? bq : ((mat == 1) ? bk : bv);
  float v1 = bias[n1], v2 = bias[n2];
  const float* Pm = P + (size_t)(mat * 8) * 524288 + (size_t)m * 4096;
#pragma unroll
  for (int s = 0; s < 8; ++s) {
    v1 += Pm[(size_t)s * 524288 + n1];
    v2 += Pm[(size_t)s * 524288 + n2];
  }
  int st = m & 15, b = m >> 4;
  int bh = b * 32 + h;
  if (mat == 2) {
    size_t dst = (size_t)(bh * TOT + PAST + st) * 128;
    vout[dst + d2] = v1; vout[dst + 64 + d2] = v2;
  } else {
    float c = rt[st * 64 + d2], sn = rt[1024 + st * 64 + d2];
    float o1 = v1 * c - v2 * sn;
    float o2 = v2 * c + v1 * sn;
    if (mat == 0) {
      size_t dst = (size_t)(bh * 16 + st) * 128;
      qr[dst + d2] = o1; qr[dst + 64 + d2] = o2;
    } else {
      size_t dst = (size_t)(bh * TOT + PAST + st) * 128;
      kout[dst + d2] = o1; kout[dst + 64 + d2] = o2;
    }
  }
}

// ------------- fused past_key copy + QK^T logits ------------------------------
// grid = 256 bh * 32 kchunks; 128 keys per block staged transposed in LDS
__global__ __launch_bounds__(256) void scores_kernel(
    const float* __restrict__ pastk, const float* __restrict__ qr,
    float* __restrict__ kout, float* __restrict__ attn) {
  int bh = blockIdx.x >> 5, kc = blockIdx.x & 31;
  int r0 = kc * 128;
  int tid = threadIdx.x;
  __shared__ float KsT[64][129];   // [d-local][key] transposed
  __shared__ float Qs[2048];
#pragma unroll
  for (int i = 0; i < 8; ++i)
    Qs[tid + i * 256] = qr[(size_t)bh * 2048 + tid + i * 256];

  const float4* pk4 = (const float4*)pastk;
  float4* ko4 = (float4*)kout;
  int qg = tid >> 6, lane = tid & 63;
  float acc[4][2] = {{0.f, 0.f}, {0.f, 0.f}, {0.f, 0.f}, {0.f, 0.f}};

  for (int p = 0; p < 2; ++p) {    // two halves of d (0..63, 64..127)
    if (p) __syncthreads();
#pragma unroll
    for (int i = 0; i < 8; ++i) {
      int f = tid + i * 256;       // 0..2047
      int r = f >> 4, g16 = f & 15;
      int g = g16 + p * 16;
      int row = r0 + r;
      float4 v;
      size_t kidx = (size_t)(bh * TOT + row) * 32 + g;
      if (row < PAST) {
        v = pk4[(size_t)(bh * PAST + row) * 32 + g];
        ko4[kidx] = v;
      } else {
        v = ko4[kidx];             // new rows written by qkv_reduce
      }
      int dl = g16 * 4;
      KsT[dl][r] = v.x; KsT[dl + 1][r] = v.y;
      KsT[dl + 2][r] = v.z; KsT[dl + 3][r] = v.w;
    }
    __syncthreads();
    int dbase = p * 64;
#pragma unroll 4
    for (int d = 0; d < 64; ++d) {
      float k0v = KsT[d][lane], k1v = KsT[d][lane + 64];
#pragma unroll
      for (int j = 0; j < 4; ++j) {
        float qv = Qs[(qg * 4 + j) * 128 + dbase + d];
        acc[j][0] = fmaf(qv, k0v, acc[j][0]);
        acc[j][1] = fmaf(qv, k1v, acc[j][1]);
      }
    }
  }
  const float scale = 0.088388347648318447f;  // 1/sqrt(128)
#pragma unroll
  for (int j = 0; j < 4; ++j) {
    int q = qg * 4 + j;
    size_t base = (size_t)(bh * 16 + q) * 4096 + r0;
    attn[base + lane] = acc[j][0] * scale;
    attn[base + 64 + lane] = acc[j][1] * scale;
  }
}

// ------------- in-place row softmax (rows of 4096) ----------------------------
__global__ __launch_bounds__(256) void softmax_kernel(float* __restrict__ attn) {
  int row = blockIdx.x;
  float4* a4 = (float4*)(attn + (size_t)row * 4096);
  int tid = threadIdx.x;
  float4 v[4];
  float mx = -1e30f;
#pragma unroll
  for (int i = 0; i < 4; ++i) {
    v[i] = a4[tid + i * 256];
    mx = fmaxf(mx, fmaxf(fmaxf(v[i].x, v[i].y), fmaxf(v[i].z, v[i].w)));
  }
#pragma unroll
  for (int off = 32; off; off >>= 1) mx = fmaxf(mx, __shfl_xor(mx, off));
  __shared__ float redm[4];
  __shared__ float reds[4];
  int wid = tid >> 6;
  if ((tid & 63) == 0) redm[wid] = mx;
  __syncthreads();
  mx = fmaxf(fmaxf(redm[0], redm[1]), fmaxf(redm[2], redm[3]));
  float sum = 0.f;
#pragma unroll
  for (int i = 0; i < 4; ++i) {
    v[i].x = __expf(v[i].x - mx); v[i].y = __expf(v[i].y - mx);
    v[i].z = __expf(v[i].z - mx); v[i].w = __expf(v[i].w - mx);
    sum += v[i].x + v[i].y + v[i].z + v[i].w;
  }
#pragma unroll
  for (int off = 32; off; off >>= 1) sum += __shfl_xor(sum, off);
  if ((tid & 63) == 0) reds[wid] = sum;
  __syncthreads();
  sum = reds[0] + reds[1] + reds[2] + reds[3];
  float inv = 1.f / sum;
#pragma unroll
  for (int i = 0; i < 4; ++i) {
    v[i].x *= inv; v[i].y *= inv; v[i].z *= inv; v[i].w *= inv;
    a4[tid + i * 256] = v[i];
  }
}

// ------------- fused past_value copy + attn@V, split over 4 key-chunks --------
// grid = 256 bh * 4 chunks of 1024 keys; 256 threads; float4 over d
__global__ __launch_bounds__(256) void pv_kernel(
    const float* __restrict__ pastv, const float* __restrict__ attn,
    float* __restrict__ vout, float* __restrict__ pvp) {
  int blk = blockIdx.x;
  int bh = blk >> 2, nc = blk & 3;
  int tid = threadIdx.x;
  int dq = tid & 31, rg = tid >> 5;      // dq: float4-in-d, rg: row group 0..7
  __shared__ float atn[16][256];          // 16 KB
  __shared__ float red[4][16][128];       // 32 KB
  float acc[16][4];
#pragma unroll
  for (int q = 0; q < 16; ++q)
#pragma unroll
    for (int j = 0; j < 4; ++j) acc[q][j] = 0.f;

  const float4* pv4 = (const float4*)pastv;
  float4* vo4 = (float4*)vout;
  int base0 = nc * 1024;

  for (int slab = 0; slab < 4; ++slab) {  // 256 keys per slab
    int kbase = base0 + slab * 256;
#pragma unroll
    for (int q = 0; q < 16; ++q)
      atn[q][tid] = attn[(size_t)(bh * 16 + q) * 4096 + kbase + tid];
    __syncthreads();
#pragma unroll 4
    for (int it = 0; it < 32; ++it) {     // 8 rows per iteration
      int kk = it * 8 + rg;               // local key in slab
      int row = kbase + kk;
      float4 v;
      size_t oidx = (size_t)(bh * TOT + row) * 32 + dq;
      if (row < PAST) {
        v = pv4[(size_t)(bh * PAST + row) * 32 + dq];
        vo4[oidx] = v;
      } else {
        v = vo4[oidx];                    // new rows written by qkv_reduce
      }
#pragma unroll
      for (int q = 0; q < 16; ++q) {
        float a = atn[q][kk];
        acc[q][0] = fmaf(a, v.x, acc[q][0]);
        acc[q][1] = fmaf(a, v.y, acc[q][1]);
        acc[q][2] = fmaf(a, v.z, acc[q][2]);
        acc[q][3] = fmaf(a, v.w, acc[q][3]);
      }
    }
    __syncthreads();
  }
  // combine the two row-groups within each wave (lanes l and l^32)
#pragma unroll
  for (int q = 0; q < 16; ++q)
#pragma unroll
    for (int j = 0; j < 4; ++j) acc[q][j] += __shfl_xor(acc[q][j], 32);
  int wid = tid >> 6;
  if ((tid & 63) < 32) {
#pragma unroll
    for (int q = 0; q < 16; ++q) {
      float4 o; o.x = acc[q][0]; o.y = acc[q][1]; o.z = acc[q][2]; o.w = acc[q][3];
      *(float4*)&red[wid][q][dq * 4] = o;
    }
  }
  __syncthreads();
#pragma unroll
  for (int rep = 0; rep < 8; ++rep) {
    int o = tid + rep * 256;              // 0..2047
    int q = o >> 7, dd = o & 127;
    float s = red[0][q][dd] + red[1][q][dd] + red[2][q][dd] + red[3][q][dd];
    pvp[((size_t)(bh * 4 + nc) * 16 + q) * 128 + dd] = s;
  }
}

// ------------- pv partial reduce -> oh ---------------------------------------
__global__ __launch_bounds__(256) void pv_reduce(
    const float* __restrict__ pvp, float* __restrict__ oh) {
  int t = blockIdx.x * 256 + threadIdx.x;  // < 524288
  int dd = t & 127;
  int q = (t >> 7) & 15;
  int bh = t >> 11;
  int b = bh >> 5, h = bh & 31;
  float s = 0.f;
#pragma unroll
  for (int nc = 0; nc < 4; ++nc)
    s += pvp[((size_t)(bh * 4 + nc) * 16 + q) * 128 + dd];
  oh[(size_t)(b * 16 + q) * 4096 + h * 128 + dd] = s;
}

// ------------- Wo partial-reduce + bias ---------------------------------------
__global__ __launch_bounds__(256) void out_reduce(
    const float* __restrict__ P, const float* __restrict__ bo,
    float* __restrict__ out) {
  int t = blockIdx.x * 256 + threadIdx.x;  // < 524288
  float v = bo[t & 4095];
#pragma unroll
  for (int s = 0; s < 8; ++s) v += P[(size_t)s * 524288 + t];
  out[t] = v;
}

extern "C" void kernel_launch(void* const* d_in, const int* in_sizes, int n_in,
                              void* d_out, int out_size, void* d_ws, size_t ws_size,
                              hipStream_t stream) {
  const float* x     = (const float*)d_in[0];
  const float* pastk = (const float*)d_in[1];
  const float* pastv = (const float*)d_in[2];
  const float* Wq = (const float*)d_in[3];
  const float* bq = (const float*)d_in[4];
  const float* Wk = (const float*)d_in[5];
  const float* bk = (const float*)d_in[6];
  const float* Wv = (const float*)d_in[7];
  const float* bv = (const float*)d_in[8];
  const float* Wo = (const float*)d_in[9];
  const float* bo = (const float*)d_in[10];

  float* out  = (float*)d_out;
  float* attn = out + ATTN_O;
  float* kout = out + K_O;
  float* vout = out + V_O;

  float* ws = (float*)d_ws;
  float* qr = ws + QR_O;
  float* oh = ws + OH_O;
  float* rt = ws + RT_O;
  float* pw = ws + PW_O;   // Wo partials; earlier in the stream: pv partials

  rope_table_kernel<<<1, 1024, 0, stream>>>(rt);
  // QKV projections: partials stored in (not-yet-final) attn region of d_out
  gemm_mfma<<<768, 256, 0, stream>>>(x, Wq, Wk, Wv, attn);
  qkv_reduce<<<3072, 256, 0, stream>>>(attn, bq, bk, bv, rt, qr, kout, vout);
  scores_kernel<<<8192, 256, 0, stream>>>(pastk, qr, kout, attn);
  softmax_kernel<<<4096, 256, 0, stream>>>(attn);
  pv_kernel<<<1024, 256, 0, stream>>>(pastv, attn, vout, pw);
  pv_reduce<<<2048, 256, 0, stream>>>(pw, oh);
  gemm_mfma<<<256, 256, 0, stream>>>(oh, Wo, Wo, Wo, pw);
  out_reduce<<<2048, 256, 0, stream>>>(pw, bo, out);
}

// Round 4
// 643.321 us; speedup vs baseline: 1.9048x; 1.1490x over previous
//
#include <hip/hip_runtime.h>
#include <hip/hip_bf16.h>

#define BB 8
#define SS 16
#define HH 32
#define DH 128
#define HD 4096
#define PAST 4080
#define TOT 4096
#define MM 128   // BB*SS

// d_out float offsets
#define OUT_O  0
#define ATTN_O 524288
#define K_O    17301504
#define V_O    151519232

// ws float offsets
#define QR_O 0
#define OH_O 524288          // oh (written by pv_reduce); earlier: stats+rows
#define STATS_O 524288       // 256*16*32*2 = 262144 floats (dead before oh is written)
#define ROWS_O  786432       // 4096*2 floats
#define RT_O 1048576
#define PW_O 1050624         // Wo-GEMM partials; ALSO reused earlier as pv partials

typedef __attribute__((ext_vector_type(8))) short short8;
typedef __attribute__((ext_vector_type(4))) float f32x4;
typedef __attribute__((ext_vector_type(4))) float f4v;

static __device__ inline unsigned short f2bf(float x) {
  __hip_bfloat16 h = __float2bfloat16(x);
  return *reinterpret_cast<unsigned short*>(&h);
}

// ---------------- RoPE cos/sin table (f64 precision, 1024 angles) -------------
__global__ void rope_table_kernel(float* __restrict__ rt) {
  int t = threadIdx.x;            // 0..1023
  int s = t >> 6, j = t & 63;
  double inv = exp(-((double)(2 * j) / 128.0) * log(10000.0));
  double ang = (double)(PAST + s) * inv;
  rt[t] = (float)cos(ang);
  rt[1024 + t] = (float)sin(ang);
}

// ------------- split-K MFMA bf16 GEMM: P[mat][ks][m][n] partials --------------
#define LDP 72   // padded LDS row stride in bf16 elements (144 B)
__global__ __launch_bounds__(256) void gemm_mfma(
    const float* __restrict__ A, const float* __restrict__ W0,
    const float* __restrict__ W1, const float* __restrict__ W2,
    float* __restrict__ P) {
  int bx = blockIdx.x;
  int mat = bx >> 8;
  int rem = bx & 255;
  int nc = rem >> 3, ks = rem & 7;
  const float* Wm = (mat == 0) ? W0 : ((mat == 1) ? W1 : W2);
  int n0 = nc * 128;
  int tid = threadIdx.x;
  int lane = tid & 63, wid = tid >> 6;
  int wm = wid >> 1, wn = wid & 1;       // 2x2 wave grid, each 64x64
  int l15 = lane & 15, l4 = lane >> 4;

  __shared__ unsigned short As[128 * LDP];
  __shared__ unsigned short Bs[128 * LDP];

  f32x4 acc[4][4];
#pragma unroll
  for (int i = 0; i < 4; ++i)
#pragma unroll
    for (int j = 0; j < 4; ++j) acc[i][j] = (f32x4){0.f, 0.f, 0.f, 0.f};

  int srow = tid >> 1;                    // 0..127
  int skh = (tid & 1) * 32;               // k half within BK=64

  for (int kt = 0; kt < 8; ++kt) {
    int k0 = ks * 512 + kt * 64;
    const float* Ap = &A[(size_t)srow * 4096 + k0 + skh];
    const float* Wp = &Wm[(size_t)(n0 + srow) * 4096 + k0 + skh];
    float4 va[8], vb[8];
#pragma unroll
    for (int i = 0; i < 8; ++i) {
      va[i] = *(const float4*)(Ap + 4 * i);
      vb[i] = *(const float4*)(Wp + 4 * i);
    }
    __syncthreads();                      // prev-iter LDS reads done
    unsigned short* Asp = &As[srow * LDP + skh];
    unsigned short* Bsp = &Bs[srow * LDP + skh];
#pragma unroll
    for (int i = 0; i < 8; ++i) {
      ushort4 ua, ub;
      ua.x = f2bf(va[i].x); ua.y = f2bf(va[i].y);
      ua.z = f2bf(va[i].z); ua.w = f2bf(va[i].w);
      ub.x = f2bf(vb[i].x); ub.y = f2bf(vb[i].y);
      ub.z = f2bf(vb[i].z); ub.w = f2bf(vb[i].w);
      *(ushort4*)(Asp + 4 * i) = ua;
      *(ushort4*)(Bsp + 4 * i) = ub;
    }
    __syncthreads();
#pragma unroll
    for (int s = 0; s < 2; ++s) {         // two K=32 steps within BK=64
      short8 af[4], bf[4];
#pragma unroll
      for (int f = 0; f < 4; ++f) {
        int ar = wm * 64 + f * 16 + l15;
        af[f] = *(const short8*)&As[ar * LDP + s * 32 + l4 * 8];
        int br = wn * 64 + f * 16 + l15;
        bf[f] = *(const short8*)&Bs[br * LDP + s * 32 + l4 * 8];
      }
#pragma unroll
      for (int i = 0; i < 4; ++i)
#pragma unroll
        for (int j = 0; j < 4; ++j)
          acc[i][j] = __builtin_amdgcn_mfma_f32_16x16x32_bf16(
              af[i], bf[j], acc[i][j], 0, 0, 0);
    }
  }

  float* Pb = P + (size_t)(mat * 8 + ks) * 524288 + n0;
#pragma unroll
  for (int i = 0; i < 4; ++i) {
#pragma unroll
    for (int j = 0; j < 4; ++j) {
      int mbase = wm * 64 + i * 16 + l4 * 4;
      int nn = wn * 64 + j * 16 + l15;
#pragma unroll
      for (int r = 0; r < 4; ++r)
        Pb[(size_t)(mbase + r) * 4096 + nn] = acc[i][j][r];
    }
  }
}

// ------------- QKV partial-reduce + bias + RoPE + scatter ---------------------
__global__ __launch_bounds__(256) void qkv_reduce(
    const float* __restrict__ P, const float* __restrict__ bq,
    const float* __restrict__ bk, const float* __restrict__ bv,
    const float* __restrict__ rt, float* __restrict__ qr,
    float* __restrict__ kout, float* __restrict__ vout) {
  int t = blockIdx.x * 256 + threadIdx.x;   // < 3*2^18
  int d2 = t & 63;
  int h = (t >> 6) & 31;
  int m = (t >> 11) & 127;
  int mat = t >> 18;
  int n1 = h * 128 + d2, n2 = n1 + 64;
  const float* bias = (mat == 0) ? bq : ((mat == 1) ? bk : bv);
  float v1 = bias[n1], v2 = bias[n2];
  const float* Pm = P + (size_t)(mat * 8) * 524288 + (size_t)m * 4096;
#pragma unroll
  for (int s = 0; s < 8; ++s) {
    v1 += Pm[(size_t)s * 524288 + n1];
    v2 += Pm[(size_t)s * 524288 + n2];
  }
  int st = m & 15, b = m >> 4;
  int bh = b * 32 + h;
  if (mat == 2) {
    size_t dst = (size_t)(bh * TOT + PAST + st) * 128;
    vout[dst + d2] = v1; vout[dst + 64 + d2] = v2;
  } else {
    float c = rt[st * 64 + d2], sn = rt[1024 + st * 64 + d2];
    float o1 = v1 * c - v2 * sn;
    float o2 = v2 * c + v1 * sn;
    if (mat == 0) {
      size_t dst = (size_t)(bh * 16 + st) * 128;
      qr[dst + d2] = o1; qr[dst + 64 + d2] = o2;
    } else {
      size_t dst = (size_t)(bh * TOT + PAST + st) * 128;
      kout[dst + d2] = o1; kout[dst + 64 + d2] = o2;
    }
  }
}

// ------------- fused past_key copy + QK^T logits + softmax stats --------------
// grid = 256 bh * 32 kchunks; 128 keys per block staged transposed in LDS
__global__ __launch_bounds__(256) void scores_kernel(
    const float* __restrict__ pastk, const float* __restrict__ qr,
    float* __restrict__ kout, float* __restrict__ attn,
    float* __restrict__ stats) {
  int bh = blockIdx.x >> 5, kc = blockIdx.x & 31;
  int r0 = kc * 128;
  int tid = threadIdx.x;
  __shared__ float KsT[64][129];   // [d-local][key] transposed
  __shared__ float Qs[2048];
#pragma unroll
  for (int i = 0; i < 8; ++i)
    Qs[tid + i * 256] = qr[(size_t)bh * 2048 + tid + i * 256];

  const f4v* pk4 = (const f4v*)pastk;
  f4v* ko4 = (f4v*)kout;
  int qg = tid >> 6, lane = tid & 63;
  float acc[4][2] = {{0.f, 0.f}, {0.f, 0.f}, {0.f, 0.f}, {0.f, 0.f}};

  for (int p = 0; p < 2; ++p) {    // two halves of d (0..63, 64..127)
    if (p) __syncthreads();
#pragma unroll
    for (int i = 0; i < 8; ++i) {
      int f = tid + i * 256;       // 0..2047
      int r = f >> 4, g16 = f & 15;
      int g = g16 + p * 16;
      int row = r0 + r;
      size_t kidx = (size_t)(bh * TOT + row) * 32 + g;
      const f4v* src = (row < PAST)
          ? (pk4 + ((size_t)(bh * PAST + row) * 32 + g))
          : (const f4v*)(ko4 + kidx);
      f4v v = __builtin_nontemporal_load(src);
      if (row < PAST) __builtin_nontemporal_store(v, ko4 + kidx);
      int dl = g16 * 4;
      KsT[dl][r] = v.x; KsT[dl + 1][r] = v.y;
      KsT[dl + 2][r] = v.z; KsT[dl + 3][r] = v.w;
    }
    __syncthreads();
    int dbase = p * 64;
#pragma unroll 4
    for (int d = 0; d < 64; ++d) {
      float k0v = KsT[d][lane], k1v = KsT[d][lane + 64];
#pragma unroll
      for (int j = 0; j < 4; ++j) {
        float qv = Qs[(qg * 4 + j) * 128 + dbase + d];
        acc[j][0] = fmaf(qv, k0v, acc[j][0]);
        acc[j][1] = fmaf(qv, k1v, acc[j][1]);
      }
    }
  }
  const float scale = 0.088388347648318447f;  // 1/sqrt(128)
#pragma unroll
  for (int j = 0; j < 4; ++j) { acc[j][0] *= scale; acc[j][1] *= scale; }
  // store scaled logits (cacheable: pv re-reads them through L3)
#pragma unroll
  for (int j = 0; j < 4; ++j) {
    int q = qg * 4 + j;
    size_t base = (size_t)(bh * 16 + q) * 4096 + r0;
    attn[base + lane] = acc[j][0];
    attn[base + 64 + lane] = acc[j][1];
  }
  // per-(row, chunk) softmax partials: max and sum-of-exp
#pragma unroll
  for (int j = 0; j < 4; ++j) {
    float m = fmaxf(acc[j][0], acc[j][1]);
#pragma unroll
    for (int off = 32; off; off >>= 1) m = fmaxf(m, __shfl_xor(m, off));
    float e = __expf(acc[j][0] - m) + __expf(acc[j][1] - m);
#pragma unroll
    for (int off = 32; off; off >>= 1) e += __shfl_xor(e, off);
    if (lane == 0) {
      int q = qg * 4 + j;
      size_t si = ((size_t)(bh * 16 + q) * 32 + kc) * 2;
      stats[si] = m; stats[si + 1] = e;
    }
  }
}

// ------------- combine per-chunk stats -> per-row (max, 1/sum) ----------------
__global__ __launch_bounds__(256) void stats_reduce(
    const float* __restrict__ stats, float* __restrict__ rows) {
  int r = blockIdx.x * 256 + threadIdx.x;  // < 4096
  float m = -1e30f;
#pragma unroll
  for (int c = 0; c < 32; ++c) m = fmaxf(m, stats[((size_t)r * 32 + c) * 2]);
  float s = 0.f;
#pragma unroll
  for (int c = 0; c < 32; ++c)
    s += stats[((size_t)r * 32 + c) * 2 + 1] *
         __expf(stats[((size_t)r * 32 + c) * 2] - m);
  rows[r * 2] = m;
  rows[r * 2 + 1] = 1.f / s;
}

// ------------- fused V copy + softmax-normalize + attn@V ----------------------
// grid = 256 bh * 4 chunks of 1024 keys; 256 threads; float4 over d
__global__ __launch_bounds__(256) void pv_kernel(
    const float* __restrict__ pastv, float* __restrict__ attn,
    const float* __restrict__ rows, float* __restrict__ vout,
    float* __restrict__ pvp) {
  int blk = blockIdx.x;
  int bh = blk >> 2, nc = blk & 3;
  int tid = threadIdx.x;
  int dq = tid & 31, rg = tid >> 5;      // dq: float4-in-d, rg: row group 0..7
  __shared__ float atn[16][256];          // 16 KB
  __shared__ float red[4][16][128];       // 32 KB
  __shared__ float sm[16], si[16];
  if (tid < 16) {
    sm[tid] = rows[(bh * 16 + tid) * 2];
    si[tid] = rows[(bh * 16 + tid) * 2 + 1];
  }
  float acc[16][4];
#pragma unroll
  for (int q = 0; q < 16; ++q)
#pragma unroll
    for (int j = 0; j < 4; ++j) acc[q][j] = 0.f;

  const f4v* pv4 = (const f4v*)pastv;
  f4v* vo4 = (f4v*)vout;
  int base0 = nc * 1024;
  __syncthreads();

  for (int slab = 0; slab < 4; ++slab) {  // 256 keys per slab
    int kbase = base0 + slab * 256;
#pragma unroll
    for (int q = 0; q < 16; ++q) {
      size_t ai = (size_t)(bh * 16 + q) * 4096 + kbase + tid;
      float x = attn[ai];
      float p = __expf(x - sm[q]) * si[q];
      atn[q][tid] = p;
      __builtin_nontemporal_store(p, &attn[ai]);  // final normalized attn
    }
    __syncthreads();
#pragma unroll 2
    for (int it = 0; it < 32; it += 2) {  // 2-deep row prefetch
      int kk0 = it * 8 + rg, kk1 = kk0 + 8;
      int row0 = kbase + kk0, row1 = kbase + kk1;
      size_t o0 = (size_t)(bh * TOT + row0) * 32 + dq;
      size_t o1 = (size_t)(bh * TOT + row1) * 32 + dq;
      const f4v* s0 = (row0 < PAST)
          ? (pv4 + ((size_t)(bh * PAST + row0) * 32 + dq)) : (const f4v*)(vo4 + o0);
      const f4v* s1 = (row1 < PAST)
          ? (pv4 + ((size_t)(bh * PAST + row1) * 32 + dq)) : (const f4v*)(vo4 + o1);
      f4v v0 = __builtin_nontemporal_load(s0);
      f4v v1 = __builtin_nontemporal_load(s1);
      if (row0 < PAST) __builtin_nontemporal_store(v0, vo4 + o0);
      if (row1 < PAST) __builtin_nontemporal_store(v1, vo4 + o1);
#pragma unroll
      for (int q = 0; q < 16; ++q) {
        float a = atn[q][kk0];
        acc[q][0] = fmaf(a, v0.x, acc[q][0]);
        acc[q][1] = fmaf(a, v0.y, acc[q][1]);
        acc[q][2] = fmaf(a, v0.z, acc[q][2]);
        acc[q][3] = fmaf(a, v0.w, acc[q][3]);
      }
#pragma unroll
      for (int q = 0; q < 16; ++q) {
        float a = atn[q][kk1];
        acc[q][0] = fmaf(a, v1.x, acc[q][0]);
        acc[q][1] = fmaf(a, v1.y, acc[q][1]);
        acc[q][2] = fmaf(a, v1.z, acc[q][2]);
        acc[q][3] = fmaf(a, v1.w, acc[q][3]);
      }
    }
    __syncthreads();
  }
  // combine the two row-groups within each wave (lanes l and l^32)
#pragma unroll
  for (int q = 0; q < 16; ++q)
#pragma unroll
    for (int j = 0; j < 4; ++j) acc[q][j] += __shfl_xor(acc[q][j], 32);
  int wid = tid >> 6;
  if ((tid & 63) < 32) {
#pragma unroll
    for (int q = 0; q < 16; ++q) {
      f4v o; o.x = acc[q][0]; o.y = acc[q][1]; o.z = acc[q][2]; o.w = acc[q][3];
      *(f4v*)&red[wid][q][dq * 4] = o;
    }
  }
  __syncthreads();
#pragma unroll
  for (int rep = 0; rep < 8; ++rep) {
    int o = tid + rep * 256;              // 0..2047
    int q = o >> 7, dd = o & 127;
    float s = red[0][q][dd] + red[1][q][dd] + red[2][q][dd] + red[3][q][dd];
    pvp[((size_t)(bh * 4 + nc) * 16 + q) * 128 + dd] = s;
  }
}

// ------------- pv partial reduce -> oh ---------------------------------------
__global__ __launch_bounds__(256) void pv_reduce(
    const float* __restrict__ pvp, float* __restrict__ oh) {
  int t = blockIdx.x * 256 + threadIdx.x;  // < 524288
  int dd = t & 127;
  int q = (t >> 7) & 15;
  int bh = t >> 11;
  int b = bh >> 5, h = bh & 31;
  float s = 0.f;
#pragma unroll
  for (int nc = 0; nc < 4; ++nc)
    s += pvp[((size_t)(bh * 4 + nc) * 16 + q) * 128 + dd];
  oh[(size_t)(b * 16 + q) * 4096 + h * 128 + dd] = s;
}

// ------------- Wo partial-reduce + bias ---------------------------------------
__global__ __launch_bounds__(256) void out_reduce(
    const float* __restrict__ P, const float* __restrict__ bo,
    float* __restrict__ out) {
  int t = blockIdx.x * 256 + threadIdx.x;  // < 524288
  float v = bo[t & 4095];
#pragma unroll
  for (int s = 0; s < 8; ++s) v += P[(size_t)s * 524288 + t];
  out[t] = v;
}

extern "C" void kernel_launch(void* const* d_in, const int* in_sizes, int n_in,
                              void* d_out, int out_size, void* d_ws, size_t ws_size,
                              hipStream_t stream) {
  const float* x     = (const float*)d_in[0];
  const float* pastk = (const float*)d_in[1];
  const float* pastv = (const float*)d_in[2];
  const float* Wq = (const float*)d_in[3];
  const float* bq = (const float*)d_in[4];
  const float* Wk = (const float*)d_in[5];
  const float* bk = (const float*)d_in[6];
  const float* Wv = (const float*)d_in[7];
  const float* bv = (const float*)d_in[8];
  const float* Wo = (const float*)d_in[9];
  const float* bo = (const float*)d_in[10];

  float* out  = (float*)d_out;
  float* attn = out + ATTN_O;
  float* kout = out + K_O;
  float* vout = out + V_O;

  float* ws = (float*)d_ws;
  float* qr    = ws + QR_O;
  float* oh    = ws + OH_O;
  float* stats = ws + STATS_O;   // dead before oh is written
  float* rows  = ws + ROWS_O;
  float* rt    = ws + RT_O;
  float* pw    = ws + PW_O;      // Wo partials; earlier: pv partials

  rope_table_kernel<<<1, 1024, 0, stream>>>(rt);
  gemm_mfma<<<768, 256, 0, stream>>>(x, Wq, Wk, Wv, attn);
  qkv_reduce<<<3072, 256, 0, stream>>>(attn, bq, bk, bv, rt, qr, kout, vout);
  scores_kernel<<<8192, 256, 0, stream>>>(pastk, qr, kout, attn, stats);
  stats_reduce<<<16, 256, 0, stream>>>(stats, rows);
  pv_kernel<<<1024, 256, 0, stream>>>(pastv, attn, rows, vout, pw);
  pv_reduce<<<2048, 256, 0, stream>>>(pw, oh);
  gemm_mfma<<<256, 256, 0, stream>>>(oh, Wo, Wo, Wo, pw);
  out_reduce<<<2048, 256, 0, stream>>>(pw, bo, out);
}